// Round 1
// baseline (437.984 us; speedup 1.0000x reference)
//
#include <hip/hip_runtime.h>
#include <hip/hip_bf16.h>
#include <math.h>

// Problem constants (fixed by the reference setup_inputs)
constexpr int B_ = 16, T_ = 1024, F_ = 80, N_ = 256;
constexpr float MIN_VAR_ = 0.001f;
constexpr float HALF_LOG_2PI_3_ = 2.7568155996140185f; // 1.5*log(2*pi)

__device__ __forceinline__ float softplus_f(float x) {
    // stable: max(x,0) + log1p(exp(-|x|))
    float e = __expf(-fabsf(x));
    return fmaxf(x, 0.0f) + __logf(1.0f + e);
}

// ---------------------------------------------------------------------------
// Kernel B: mel mixture log-prob sum.
// One 320-thread block per 4 (b,t) rows. Stage 4 rows (4*4000 f32 = 64 KB)
// into LDS coalesced, then each thread computes exactly one (row, f) task.
// ---------------------------------------------------------------------------
__global__ __launch_bounds__(320, 1) void mel_kernel(
    const float* __restrict__ mel_out,
    const unsigned char* __restrict__ dec_mask,
    const float* __restrict__ mel_tgt,
    float* __restrict__ ws)
{
    __shared__ float lds[4 * 4000];
    __shared__ float wpart[5];

    const int tid = threadIdx.x;
    const int r0 = blockIdx.x * 4;   // first row (b*T+t) of this block

    // ---- stage 4 rows: 4000 float4 over 320 threads (13 iters, last partial)
    const float4* __restrict__ src4 =
        reinterpret_cast<const float4*>(mel_out) + (size_t)r0 * 1000;
    float4* l4 = reinterpret_cast<float4*>(lds);
    #pragma unroll
    for (int i = 0; i < 13; ++i) {
        int idx = tid + i * 320;
        if (idx < 4000) l4[idx] = src4[idx];
    }
    __syncthreads();

    // ---- compute: thread -> (row_local, f)
    const int rl  = tid / 80;        // 0..3
    const int f   = tid - rl * 80;   // 0..79
    const int row = r0 + rl;
    const int b   = row >> 10;       // T = 1024
    const int t   = row & 1023;
    const float mask = dec_mask[row] ? 1.0f : 0.0f;

    const float* __restrict__ pp = &lds[rl * 4000 + f * 50];
    const float* __restrict__ mt = mel_tgt + ((size_t)(b * 80 + f)) * 1024 + t;

    const float y0 = mt[0];
    const float y1 = (t < 1023) ? mt[1] : 0.0f;       // next time step
    const float y2 = (f < 79)   ? mt[1024] : 0.0f;    // next mel bin

    float s[5], wv[5];
    #pragma unroll
    for (int k = 0; k < 5; ++k) {
        const float* q = pp + k * 10;
        float2 c0 = *reinterpret_cast<const float2*>(q + 0); // w, mu0
        float2 c1 = *reinterpret_cast<const float2*>(q + 2); // mu1, mu2
        float2 c2 = *reinterpret_cast<const float2*>(q + 4); // q0, q1
        float2 c3 = *reinterpret_cast<const float2*>(q + 6); // q2, l10
        float2 c4 = *reinterpret_cast<const float2*>(q + 8); // l21, l20

        float w  = c0.x;
        float d0 = y0 - c0.y;
        float d1 = y1 - c1.x;
        float d2 = y2 - c1.y;

        float dg0 = softplus_f(c2.x) + MIN_VAR_;
        float dg1 = softplus_f(c2.y) + MIN_VAR_;
        float dg2 = softplus_f(c3.x) + MIN_VAR_;
        float l10 = c3.y, l21 = c4.x, l20 = c4.y;

        float z0 = d0 * __builtin_amdgcn_rcpf(dg0);
        float z1 = (d1 - l10 * z0) * __builtin_amdgcn_rcpf(dg1);
        float z2 = (d2 - l20 * z0 - l21 * z1) * __builtin_amdgcn_rcpf(dg2);

        float maha = z0 * z0 + z1 * z1 + z2 * z2;
        float comp = -0.5f * maha - __logf(dg0 * dg1 * dg2) - HALF_LOG_2PI_3_;

        wv[k] = w;
        s[k]  = w + comp;
    }

    // logp = lse(w + comp) - lse(w)   (== lse(log_softmax(w) + comp))
    float ms = s[0], mw = wv[0];
    #pragma unroll
    for (int k = 1; k < 5; ++k) { ms = fmaxf(ms, s[k]); mw = fmaxf(mw, wv[k]); }
    float es = 0.0f, ew = 0.0f;
    #pragma unroll
    for (int k = 0; k < 5; ++k) {
        es += __expf(s[k] - ms);
        ew += __expf(wv[k] - mw);
    }
    float logp = (ms + __logf(es)) - (mw + __logf(ew));

    float v = logp * mask;
    // wave (64-lane) butterfly reduce
    #pragma unroll
    for (int off = 32; off >= 1; off >>= 1) v += __shfl_xor(v, off);
    const int wid = tid >> 6;
    if ((tid & 63) == 0) wpart[wid] = v;
    __syncthreads();
    if (tid == 0) {
        float tot = wpart[0] + wpart[1] + wpart[2] + wpart[3] + wpart[4];
        atomicAdd(&ws[0], tot);
    }
}

// ---------------------------------------------------------------------------
// Kernel C: dur/pitch/mask sums + finalize the 4 outputs.
// ---------------------------------------------------------------------------
__global__ __launch_bounds__(256) void finalize_kernel(
    const unsigned char* __restrict__ dec_mask,
    const float* __restrict__ log_dur_pred,
    const float* __restrict__ pitch_pred,
    const int* __restrict__ dur_tgt,
    const int* __restrict__ dur_lens,
    const float* __restrict__ pitch_tgt,
    const float* __restrict__ ws,
    float* __restrict__ out)
{
    __shared__ float red[4][4];
    const int tid = threadIdx.x;
    float dm = 0.0f, dur = 0.0f, pit = 0.0f, msum = 0.0f;

    for (int i = tid; i < B_ * N_; i += 256) {
        int b = i >> 8;        // N = 256
        int n = i & 255;
        if (n < dur_lens[b]) {
            dm += 1.0f;
            float ldt = __logf((float)dur_tgt[i] + 1.0f);
            float dd  = log_dur_pred[i] - ldt;
            dur += dd * dd;
            float pd  = pitch_tgt[i] - pitch_pred[i];
            pit += pd * pd;
        }
    }
    for (int i = tid; i < B_ * T_; i += 256) msum += dec_mask[i] ? 1.0f : 0.0f;

    #pragma unroll
    for (int off = 32; off >= 1; off >>= 1) {
        dm   += __shfl_xor(dm, off);
        dur  += __shfl_xor(dur, off);
        pit  += __shfl_xor(pit, off);
        msum += __shfl_xor(msum, off);
    }
    const int wid = tid >> 6;
    if ((tid & 63) == 0) {
        red[0][wid] = dm; red[1][wid] = dur; red[2][wid] = pit; red[3][wid] = msum;
    }
    __syncthreads();
    if (tid == 0) {
        dm   = red[0][0] + red[0][1] + red[0][2] + red[0][3];
        dur  = red[1][0] + red[1][1] + red[1][2] + red[1][3];
        pit  = red[2][0] + red[2][1] + red[2][2] + red[2][3];
        msum = red[3][0] + red[3][1] + red[3][2] + red[3][3];

        float mel_loss   = -ws[0] / (msum * (float)F_);
        float dur_loss   = dur / dm;
        float pitch_loss = pit / dm;
        out[0] = mel_loss + pitch_loss * 1.0f /*PITCH_SCALE*/ + dur_loss * 1.0f /*DUR_SCALE*/;
        out[1] = mel_loss;
        out[2] = dur_loss;
        out[3] = pitch_loss;
    }
}

extern "C" void kernel_launch(void* const* d_in, const int* in_sizes, int n_in,
                              void* d_out, int out_size, void* d_ws, size_t ws_size,
                              hipStream_t stream) {
    const float*         mel_out      = (const float*)d_in[0];
    const unsigned char* dec_mask     = (const unsigned char*)d_in[1];
    // d_in[2] = dur_pred (unused by the reference)
    const float*         log_dur_pred = (const float*)d_in[3];
    const float*         pitch_pred   = (const float*)d_in[4];
    const float*         mel_tgt      = (const float*)d_in[5];
    const int*           dur_tgt      = (const int*)d_in[6];
    const int*           dur_lens     = (const int*)d_in[7];
    const float*         pitch_tgt    = (const float*)d_in[8];
    float*               ws           = (float*)d_ws;

    hipMemsetAsync(ws, 0, 16, stream);

    // 16384 rows / 4 rows per block = 4096 blocks
    mel_kernel<<<dim3(4096), dim3(320), 0, stream>>>(mel_out, dec_mask, mel_tgt, ws);

    finalize_kernel<<<dim3(1), dim3(256), 0, stream>>>(
        dec_mask, log_dur_pred, pitch_pred, dur_tgt, dur_lens, pitch_tgt,
        ws, (float*)d_out);
}

// Round 2
// 425.351 us; speedup vs baseline: 1.0297x; 1.0297x over previous
//
#include <hip/hip_runtime.h>
#include <hip/hip_bf16.h>
#include <math.h>

// Problem constants (fixed by the reference setup_inputs)
constexpr int B_ = 16, T_ = 1024, F_ = 80, N_ = 256;
constexpr int NBLK = 4096;           // mel blocks (4 rows each)
constexpr float MIN_VAR_ = 0.001f;
constexpr float HALF_LOG_2PI_3_ = 2.7568155996140185f; // 1.5*log(2*pi)

__device__ __forceinline__ float softplus_f(float x) {
    // stable: max(x,0) + log1p(exp(-|x|))
    float e = __expf(-fabsf(x));
    return fmaxf(x, 0.0f) + __logf(1.0f + e);
}

// ---------------------------------------------------------------------------
// Kernel B: mel mixture log-prob sum.
// One 320-thread block per 4 (b,t) rows. Stage 4 rows (4*4000 f32 = 64 KB)
// into LDS coalesced, then each thread computes exactly one (row, f) task.
// Partial sum per block -> ws[blockIdx.x]  (NO same-address atomics: 4096
// device-scope RMWs to one line serialize across XCDs).
// ---------------------------------------------------------------------------
__global__ __launch_bounds__(320, 1) void mel_kernel(
    const float* __restrict__ mel_out,
    const unsigned char* __restrict__ dec_mask,
    const float* __restrict__ mel_tgt,
    float* __restrict__ ws)
{
    __shared__ float lds[4 * 4000];
    __shared__ float wpart[5];

    const int tid = threadIdx.x;
    const int r0 = blockIdx.x * 4;   // first row (b*T+t) of this block

    // ---- per-thread task coords (load y0/y1/y2 BEFORE the barrier so they
    //      overlap the staging burst; __syncthreads would fence them after)
    const int rl  = tid / 80;        // 0..3
    const int f   = tid - rl * 80;   // 0..79
    const int row = r0 + rl;
    const int b   = row >> 10;       // T = 1024
    const int t   = row & 1023;
    const float mask = dec_mask[row] ? 1.0f : 0.0f;

    const float* __restrict__ mt = mel_tgt + ((size_t)(b * 80 + f)) * 1024 + t;
    const float y0 = mt[0];
    const float y1 = (t < 1023) ? mt[1] : 0.0f;       // next time step
    const float y2 = (f < 79)   ? mt[1024] : 0.0f;    // next mel bin

    // ---- stage 4 rows: 4000 float4 over 320 threads (13 iters, last partial)
    const float4* __restrict__ src4 =
        reinterpret_cast<const float4*>(mel_out) + (size_t)r0 * 1000;
    float4* l4 = reinterpret_cast<float4*>(lds);
    #pragma unroll
    for (int i = 0; i < 13; ++i) {
        int idx = tid + i * 320;
        if (idx < 4000) l4[idx] = src4[idx];
    }
    __syncthreads();

    const float* __restrict__ pp = &lds[rl * 4000 + f * 50];

    float s[5], wv[5];
    #pragma unroll
    for (int k = 0; k < 5; ++k) {
        const float* q = pp + k * 10;
        float2 c0 = *reinterpret_cast<const float2*>(q + 0); // w, mu0
        float2 c1 = *reinterpret_cast<const float2*>(q + 2); // mu1, mu2
        float2 c2 = *reinterpret_cast<const float2*>(q + 4); // q0, q1
        float2 c3 = *reinterpret_cast<const float2*>(q + 6); // q2, l10
        float2 c4 = *reinterpret_cast<const float2*>(q + 8); // l21, l20

        float w  = c0.x;
        float d0 = y0 - c0.y;
        float d1 = y1 - c1.x;
        float d2 = y2 - c1.y;

        float dg0 = softplus_f(c2.x) + MIN_VAR_;
        float dg1 = softplus_f(c2.y) + MIN_VAR_;
        float dg2 = softplus_f(c3.x) + MIN_VAR_;
        float l10 = c3.y, l21 = c4.x, l20 = c4.y;

        float z0 = d0 * __builtin_amdgcn_rcpf(dg0);
        float z1 = (d1 - l10 * z0) * __builtin_amdgcn_rcpf(dg1);
        float z2 = (d2 - l20 * z0 - l21 * z1) * __builtin_amdgcn_rcpf(dg2);

        float maha = z0 * z0 + z1 * z1 + z2 * z2;
        float comp = -0.5f * maha - __logf(dg0 * dg1 * dg2) - HALF_LOG_2PI_3_;

        wv[k] = w;
        s[k]  = w + comp;
    }

    // logp = lse(w + comp) - lse(w)   (== lse(log_softmax(w) + comp))
    float ms = s[0], mw = wv[0];
    #pragma unroll
    for (int k = 1; k < 5; ++k) { ms = fmaxf(ms, s[k]); mw = fmaxf(mw, wv[k]); }
    float es = 0.0f, ew = 0.0f;
    #pragma unroll
    for (int k = 0; k < 5; ++k) {
        es += __expf(s[k] - ms);
        ew += __expf(wv[k] - mw);
    }
    float logp = (ms + __logf(es)) - (mw + __logf(ew));

    float v = logp * mask;
    // wave (64-lane) butterfly reduce
    #pragma unroll
    for (int off = 32; off >= 1; off >>= 1) v += __shfl_xor(v, off);
    const int wid = tid >> 6;
    if ((tid & 63) == 0) wpart[wid] = v;
    __syncthreads();
    if (tid == 0) {
        ws[blockIdx.x] = wpart[0] + wpart[1] + wpart[2] + wpart[3] + wpart[4];
    }
}

// ---------------------------------------------------------------------------
// Kernel C: reduce mel partials + dur/pitch/mask sums + finalize 4 outputs.
// ---------------------------------------------------------------------------
__global__ __launch_bounds__(256) void finalize_kernel(
    const unsigned char* __restrict__ dec_mask,
    const float* __restrict__ log_dur_pred,
    const float* __restrict__ pitch_pred,
    const int* __restrict__ dur_tgt,
    const int* __restrict__ dur_lens,
    const float* __restrict__ pitch_tgt,
    const float* __restrict__ partials,
    float* __restrict__ out)
{
    __shared__ float red[5][4];
    const int tid = threadIdx.x;
    float dm = 0.0f, dur = 0.0f, pit = 0.0f, msum = 0.0f, mel = 0.0f;

    for (int i = tid; i < NBLK; i += 256) mel += partials[i];

    for (int i = tid; i < B_ * N_; i += 256) {
        int b = i >> 8;        // N = 256
        int n = i & 255;
        if (n < dur_lens[b]) {
            dm += 1.0f;
            float ldt = __logf((float)dur_tgt[i] + 1.0f);
            float dd  = log_dur_pred[i] - ldt;
            dur += dd * dd;
            float pd  = pitch_tgt[i] - pitch_pred[i];
            pit += pd * pd;
        }
    }
    for (int i = tid; i < B_ * T_; i += 256) msum += dec_mask[i] ? 1.0f : 0.0f;

    #pragma unroll
    for (int off = 32; off >= 1; off >>= 1) {
        dm   += __shfl_xor(dm, off);
        dur  += __shfl_xor(dur, off);
        pit  += __shfl_xor(pit, off);
        msum += __shfl_xor(msum, off);
        mel  += __shfl_xor(mel, off);
    }
    const int wid = tid >> 6;
    if ((tid & 63) == 0) {
        red[0][wid] = dm; red[1][wid] = dur; red[2][wid] = pit;
        red[3][wid] = msum; red[4][wid] = mel;
    }
    __syncthreads();
    if (tid == 0) {
        dm   = red[0][0] + red[0][1] + red[0][2] + red[0][3];
        dur  = red[1][0] + red[1][1] + red[1][2] + red[1][3];
        pit  = red[2][0] + red[2][1] + red[2][2] + red[2][3];
        msum = red[3][0] + red[3][1] + red[3][2] + red[3][3];
        mel  = red[4][0] + red[4][1] + red[4][2] + red[4][3];

        float mel_loss   = -mel / (msum * (float)F_);
        float dur_loss   = dur / dm;
        float pitch_loss = pit / dm;
        out[0] = mel_loss + pitch_loss * 1.0f /*PITCH_SCALE*/ + dur_loss * 1.0f /*DUR_SCALE*/;
        out[1] = mel_loss;
        out[2] = dur_loss;
        out[3] = pitch_loss;
    }
}

extern "C" void kernel_launch(void* const* d_in, const int* in_sizes, int n_in,
                              void* d_out, int out_size, void* d_ws, size_t ws_size,
                              hipStream_t stream) {
    const float*         mel_out      = (const float*)d_in[0];
    const unsigned char* dec_mask     = (const unsigned char*)d_in[1];
    // d_in[2] = dur_pred (unused by the reference)
    const float*         log_dur_pred = (const float*)d_in[3];
    const float*         pitch_pred   = (const float*)d_in[4];
    const float*         mel_tgt      = (const float*)d_in[5];
    const int*           dur_tgt      = (const int*)d_in[6];
    const int*           dur_lens     = (const int*)d_in[7];
    const float*         pitch_tgt    = (const float*)d_in[8];
    float*               ws           = (float*)d_ws;

    // 16384 rows / 4 rows per block = 4096 blocks; each writes ws[blockIdx]
    mel_kernel<<<dim3(NBLK), dim3(320), 0, stream>>>(mel_out, dec_mask, mel_tgt, ws);

    finalize_kernel<<<dim3(1), dim3(256), 0, stream>>>(
        dec_mask, log_dur_pred, pitch_pred, dur_tgt, dur_lens, pitch_tgt,
        ws, (float*)d_out);
}

// Round 3
// 407.708 us; speedup vs baseline: 1.0743x; 1.0433x over previous
//
#include <hip/hip_runtime.h>
#include <math.h>

// Problem constants (fixed by the reference setup_inputs)
constexpr int B_ = 16, T_ = 1024, F_ = 80, N_ = 256;
constexpr int GRID_MEL = 256;           // 1 block per CU
constexpr int ROWS_PER_BLOCK = 64;      // 16384 rows / 256 blocks
constexpr int GROUPS = 16;              // 4 rows per group, double-buffered
constexpr int SLOTS = 13;               // async 1KB chunks per wave per group (5 waves * 13 = 65)
constexpr long long TOTAL_F4 = 16384LL * 1000;  // mel_out size in float4
constexpr float MIN_VAR_ = 0.001f;
constexpr float HALF_LOG_2PI_3_ = 2.7568155996140185f; // 1.5*log(2*pi)

__device__ __forceinline__ float softplus_f(float x) {
    float e = __expf(-fabsf(x));
    return fmaxf(x, 0.0f) + __logf(1.0f + e);
}

__device__ __forceinline__ void gload_lds16(const float* g, float* l) {
    // async global->LDS, 16B per lane; LDS dest = wave-uniform base + lane*16
    __builtin_amdgcn_global_load_lds(
        (const __attribute__((address_space(1))) void*)g,
        (__attribute__((address_space(3))) void*)l,
        16, 0, 0);
}

// ---------------------------------------------------------------------------
// Persistent mel kernel: 256 blocks x 320 threads. Each block owns 64 rows
// (all same b; t in [t0, t0+64)). Double-buffered 4-row groups staged via
// global_load_lds; counted vmcnt(13) so next group's loads stay in flight
// across raw s_barriers. y-tile (mel_tgt) + dec_mask staged once in prologue
// so the main loop has ZERO non-async VMEM ops (vmcnt queue stays pure).
// ---------------------------------------------------------------------------
__global__ __launch_bounds__(320) void mel_kernel(
    const float* __restrict__ mel_out,
    const unsigned char* __restrict__ dec_mask,
    const float* __restrict__ mel_tgt,
    float* __restrict__ ws)
{
    __shared__ float buf[2][65 * 256];   // 2 x 66560 B (65 chunks of 1KB)
    __shared__ float lds_y[80 * 65];     // mel_tgt[b, f, t0..t0+64] (zero-padded)
    __shared__ float lds_mask[64];
    __shared__ float wpart[5];

    const int tid  = threadIdx.x;
    const int wave = tid >> 6;
    const int lane = tid & 63;
    const int R0   = blockIdx.x * ROWS_PER_BLOCK;
    const int bb   = R0 >> 10;           // T = 1024; 64-row blocks never straddle b
    const int t0   = R0 & 1023;

    // ---- issue async stage of group 0 ASAP (memory head-start)
    {
        const long long gb = (long long)R0 * 1000;   // float4 base of group 0
        #pragma unroll
        for (int i = 0; i < SLOTS; ++i) {
            int c = wave + 5 * i;                    // 0..64, unique per wave
            long long g4 = gb + (long long)c * 64;
            if (g4 > TOTAL_F4 - 64) g4 = TOTAL_F4 - 64;   // clamp tail over-read
            gload_lds16(mel_out + (g4 + lane) * 4, &buf[0][c * 256]);
        }
    }

    // ---- stage y tile: lds_y[f*65+j] = mel_tgt[bb, f, t0+j] (0 if t OOB)
    for (int idx = tid; idx < 80 * 65; idx += 320) {
        int f = idx / 65, j = idx - f * 65;
        int t = t0 + j;
        lds_y[idx] = (t < 1024) ? mel_tgt[(((long long)(bb * 80 + f)) << 10) + t] : 0.0f;
    }
    if (tid < 64) lds_mask[tid] = dec_mask[R0 + tid] ? 1.0f : 0.0f;

    __syncthreads();   // full drain: group 0 + y-tile + mask all ready

    const int rl = tid / 80;             // 0..3 (row within group)
    const int f  = tid - rl * 80;        // 0..79

    float acc = 0.0f;

    for (int g = 0; g < GROUPS; ++g) {
        const int nb = g & 1;
        if (g + 1 < GROUPS) {
            // prefetch group g+1 into the other buffer (freed by prev trailing barrier)
            const long long gb = (long long)(R0 + (g + 1) * 4) * 1000;
            #pragma unroll
            for (int i = 0; i < SLOTS; ++i) {
                int c = wave + 5 * i;
                long long g4 = gb + (long long)c * 64;
                if (g4 > TOTAL_F4 - 64) g4 = TOTAL_F4 - 64;
                gload_lds16(mel_out + (g4 + lane) * 4, &buf[nb ^ 1][c * 256]);
            }
            // wait for group g's 13 asyncs; keep g+1's 13 in flight
            asm volatile("s_waitcnt vmcnt(13)" ::: "memory");
        } else {
            asm volatile("s_waitcnt vmcnt(0)" ::: "memory");
        }
        __builtin_amdgcn_sched_barrier(0);
        __builtin_amdgcn_s_barrier();
        asm volatile("" ::: "memory");

        // ---- compute group g (LDS only)
        const int row_loc = g * 4 + rl;                 // 0..63 == t - t0
        const float mask = lds_mask[row_loc];
        const float y0 = lds_y[f * 65 + row_loc];
        const float y1 = lds_y[f * 65 + row_loc + 1];   // width 65: in-bounds, 0-padded
        const float y2 = (f < 79) ? lds_y[(f + 1) * 65 + row_loc] : 0.0f;
        const float* pp = &buf[nb][rl * 4000 + f * 50];

        float s[5], wv[5];
        #pragma unroll
        for (int k = 0; k < 5; ++k) {
            const float* q = pp + k * 10;
            float2 c0 = *reinterpret_cast<const float2*>(q + 0); // w, mu0
            float2 c1 = *reinterpret_cast<const float2*>(q + 2); // mu1, mu2
            float2 c2 = *reinterpret_cast<const float2*>(q + 4); // q0, q1
            float2 c3 = *reinterpret_cast<const float2*>(q + 6); // q2, l10
            float2 c4 = *reinterpret_cast<const float2*>(q + 8); // l21, l20

            float w  = c0.x;
            float d0 = y0 - c0.y;
            float d1 = y1 - c1.x;
            float d2 = y2 - c1.y;

            float dg0 = softplus_f(c2.x) + MIN_VAR_;
            float dg1 = softplus_f(c2.y) + MIN_VAR_;
            float dg2 = softplus_f(c3.x) + MIN_VAR_;

            float z0 = d0 * __builtin_amdgcn_rcpf(dg0);
            float z1 = (d1 - c3.y * z0) * __builtin_amdgcn_rcpf(dg1);
            float z2 = (d2 - c4.y * z0 - c4.x * z1) * __builtin_amdgcn_rcpf(dg2);

            float maha = z0 * z0 + z1 * z1 + z2 * z2;
            wv[k] = w;
            s[k]  = w - 0.5f * maha - __logf(dg0 * dg1 * dg2) - HALF_LOG_2PI_3_;
        }

        // logp = lse(w + comp) - lse(w)
        float ms = s[0], mw = wv[0];
        #pragma unroll
        for (int k = 1; k < 5; ++k) { ms = fmaxf(ms, s[k]); mw = fmaxf(mw, wv[k]); }
        float es = 0.0f, ew = 0.0f;
        #pragma unroll
        for (int k = 0; k < 5; ++k) {
            es += __expf(s[k] - ms);
            ew += __expf(wv[k] - mw);
        }
        float logp = (ms + __logf(es)) - (mw + __logf(ew));
        acc += logp * mask;

        asm volatile("" ::: "memory");
        __builtin_amdgcn_sched_barrier(0);
        __builtin_amdgcn_s_barrier();   // compute done before next overwrite
    }

    // ---- block reduction -> one partial per block
    #pragma unroll
    for (int off = 32; off >= 1; off >>= 1) acc += __shfl_xor(acc, off);
    if (lane == 0) wpart[wave] = acc;
    __syncthreads();
    if (tid == 0) {
        ws[blockIdx.x] = wpart[0] + wpart[1] + wpart[2] + wpart[3] + wpart[4];
    }
}

// ---------------------------------------------------------------------------
// Finalize: reduce 256 mel partials + dur/pitch/mask sums + 4 outputs.
// ---------------------------------------------------------------------------
__global__ __launch_bounds__(256) void finalize_kernel(
    const unsigned char* __restrict__ dec_mask,
    const float* __restrict__ log_dur_pred,
    const float* __restrict__ pitch_pred,
    const int* __restrict__ dur_tgt,
    const int* __restrict__ dur_lens,
    const float* __restrict__ pitch_tgt,
    const float* __restrict__ partials,
    float* __restrict__ out)
{
    __shared__ float red[5][4];
    const int tid = threadIdx.x;
    float dm = 0.0f, dur = 0.0f, pit = 0.0f, msum = 0.0f, mel = 0.0f;

    for (int i = tid; i < GRID_MEL; i += 256) mel += partials[i];

    for (int i = tid; i < B_ * N_; i += 256) {
        int b = i >> 8;        // N = 256
        int n = i & 255;
        if (n < dur_lens[b]) {
            dm += 1.0f;
            float ldt = __logf((float)dur_tgt[i] + 1.0f);
            float dd  = log_dur_pred[i] - ldt;
            dur += dd * dd;
            float pd  = pitch_tgt[i] - pitch_pred[i];
            pit += pd * pd;
        }
    }
    for (int i = tid; i < B_ * T_; i += 256) msum += dec_mask[i] ? 1.0f : 0.0f;

    #pragma unroll
    for (int off = 32; off >= 1; off >>= 1) {
        dm   += __shfl_xor(dm, off);
        dur  += __shfl_xor(dur, off);
        pit  += __shfl_xor(pit, off);
        msum += __shfl_xor(msum, off);
        mel  += __shfl_xor(mel, off);
    }
    const int wid = tid >> 6;
    if ((tid & 63) == 0) {
        red[0][wid] = dm; red[1][wid] = dur; red[2][wid] = pit;
        red[3][wid] = msum; red[4][wid] = mel;
    }
    __syncthreads();
    if (tid == 0) {
        dm   = red[0][0] + red[0][1] + red[0][2] + red[0][3];
        dur  = red[1][0] + red[1][1] + red[1][2] + red[1][3];
        pit  = red[2][0] + red[2][1] + red[2][2] + red[2][3];
        msum = red[3][0] + red[3][1] + red[3][2] + red[3][3];
        mel  = red[4][0] + red[4][1] + red[4][2] + red[4][3];

        float mel_loss   = -mel / (msum * (float)F_);
        float dur_loss   = dur / dm;
        float pitch_loss = pit / dm;
        out[0] = mel_loss + pitch_loss * 1.0f /*PITCH_SCALE*/ + dur_loss * 1.0f /*DUR_SCALE*/;
        out[1] = mel_loss;
        out[2] = dur_loss;
        out[3] = pitch_loss;
    }
}

extern "C" void kernel_launch(void* const* d_in, const int* in_sizes, int n_in,
                              void* d_out, int out_size, void* d_ws, size_t ws_size,
                              hipStream_t stream) {
    const float*         mel_out      = (const float*)d_in[0];
    const unsigned char* dec_mask     = (const unsigned char*)d_in[1];
    // d_in[2] = dur_pred (unused by the reference)
    const float*         log_dur_pred = (const float*)d_in[3];
    const float*         pitch_pred   = (const float*)d_in[4];
    const float*         mel_tgt      = (const float*)d_in[5];
    const int*           dur_tgt      = (const int*)d_in[6];
    const int*           dur_lens     = (const int*)d_in[7];
    const float*         pitch_tgt    = (const float*)d_in[8];
    float*               ws           = (float*)d_ws;

    mel_kernel<<<dim3(GRID_MEL), dim3(320), 0, stream>>>(mel_out, dec_mask, mel_tgt, ws);

    finalize_kernel<<<dim3(1), dim3(256), 0, stream>>>(
        dec_mask, log_dur_pred, pitch_pred, dur_tgt, dur_lens, pitch_tgt,
        ws, (float*)d_out);
}